// Round 1
// baseline (2385.644 us; speedup 1.0000x reference)
//
#include <hip/hip_runtime.h>

#define PI2F 6.283185307179586476f

// ---------------------------------------------------------------------------
// Radix-4 Stockham autosort FFT (DIF), split re/im layout.
// Pass structure (OTFFT style): for current sub-length n, stride s (s*n/4 = N/4):
//   src indices: t, t+N/4, t+2N/4, t+3N/4      (t = q + s*p, perfectly coalesced)
//   dst indices: q + s*(4p + r), r = 0..3
//   y0 = (a+c)+(b+d)
//   y1 = ((a-c) - i(b-d)) * W_n^p
//   y2 = ((a+c)-(b+d))    * W_n^{2p}
//   y3 = ((a-c) + i(b-d)) * W_n^{3p}
// ---------------------------------------------------------------------------

// First pass: n = N, s = 1, real input (imag = 0), contiguous float4 stores.
__global__ __launch_bounds__(256) void fft4_first(const float* __restrict__ x,
                                                  float* __restrict__ yre,
                                                  float* __restrict__ yim,
                                                  int Nq, float n_inv)
{
    int p = blockIdx.x * 256 + threadIdx.x;
    if (p >= Nq) return;

    float a = x[p];
    float b = x[p + Nq];
    float c = x[p + 2 * Nq];
    float d = x[p + 3 * Nq];

    float apc = a + c, amc = a - c;
    float bpd = b + d, bmd = b - d;

    float ang = -PI2F * ((float)p * n_inv);
    float w1i, w1r;
    __sincosf(ang, &w1i, &w1r);
    float w2r = w1r * w1r - w1i * w1i, w2i = 2.f * w1r * w1i;
    float w3r = w2r * w1r - w2i * w1i, w3i = w2r * w1i + w2i * w1r;

    // y0 = (apc+bpd, 0)
    // y1 = (amc, -bmd) * w1
    // y2 = (apc-bpd, 0) * w2
    // y3 = (amc, +bmd) * w3
    float t2 = apc - bpd;
    float4 r4, i4;
    r4.x = apc + bpd;                 i4.x = 0.f;
    r4.y = amc * w1r + bmd * w1i;     i4.y = amc * w1i - bmd * w1r;
    r4.z = t2 * w2r;                  i4.z = t2 * w2i;
    r4.w = amc * w3r - bmd * w3i;     i4.w = amc * w3i + bmd * w3r;

    *(float4*)(yre + 4 * p) = r4;
    *(float4*)(yim + 4 * p) = i4;
}

// Generic radix-4 Stockham pass. sl = log2(s). n = N >> sl, n_inv = 1/n.
__global__ __launch_bounds__(256) void fft4_pass(const float* __restrict__ xre,
                                                 const float* __restrict__ xim,
                                                 float* __restrict__ yre,
                                                 float* __restrict__ yim,
                                                 int Nq, int sl, float n_inv)
{
    int t = blockIdx.x * 256 + threadIdx.x;
    if (t >= Nq) return;

    const int s = 1 << sl;
    const int q = t & (s - 1);
    const int p = t >> sl;

    float ar = xre[t],          ai = xim[t];
    float br = xre[t + Nq],     bi = xim[t + Nq];
    float cr = xre[t + 2 * Nq], ci = xim[t + 2 * Nq];
    float dr = xre[t + 3 * Nq], di = xim[t + 3 * Nq];

    float apcr = ar + cr, apci = ai + ci;
    float amcr = ar - cr, amci = ai - ci;
    float bpdr = br + dr, bpdi = bi + di;
    float bmdr = br - dr, bmdi = bi - di;

    float ang = -PI2F * ((float)p * n_inv);
    float w1i, w1r;
    __sincosf(ang, &w1i, &w1r);
    float w2r = w1r * w1r - w1i * w1i, w2i = 2.f * w1r * w1i;
    float w3r = w2r * w1r - w2i * w1i, w3i = w2r * w1i + w2i * w1r;

    const int dst = q + (p << (sl + 2));

    yre[dst] = apcr + bpdr;
    yim[dst] = apci + bpdi;

    // y1 = (amc - i*bmd) * w1 ; (amc - i*bmd) = (amcr + bmdi, amci - bmdr)
    float t1r = amcr + bmdi, t1i = amci - bmdr;
    yre[dst + s] = t1r * w1r - t1i * w1i;
    yim[dst + s] = t1r * w1i + t1i * w1r;

    float t2r = apcr - bpdr, t2i = apci - bpdi;
    yre[dst + 2 * s] = t2r * w2r - t2i * w2i;
    yim[dst + 2 * s] = t2r * w2i + t2i * w2r;

    // y3 = (amc + i*bmd) * w3 ; (amc + i*bmd) = (amcr - bmdi, amci + bmdr)
    float t3r = amcr - bmdi, t3i = amci + bmdr;
    yre[dst + 3 * s] = t3r * w3r - t3i * w3i;
    yim[dst + 3 * s] = t3r * w3i + t3i * w3r;
}

// ---------------------------------------------------------------------------
// Fallback (only if ws too small or log2(N) odd): in-place radix-2 DIT in
// d_out with bit-reversal gather. 26 stages. Slower but needs no workspace.
// ---------------------------------------------------------------------------
__global__ __launch_bounds__(256) void bitrev_load(const float* __restrict__ x,
                                                   float* __restrict__ re,
                                                   float* __restrict__ im,
                                                   int N, int logN)
{
    int i = blockIdx.x * 256 + threadIdx.x;
    if (i >= N) return;
    unsigned r = __brev((unsigned)i) >> (32 - logN);
    re[i] = x[r];
    im[i] = 0.f;
}

__global__ __launch_bounds__(256) void r2_stage(float* __restrict__ re,
                                                float* __restrict__ im,
                                                int Nh, int sl, float m_inv)
{
    int t = blockIdx.x * 256 + threadIdx.x;
    if (t >= Nh) return;
    const int half = 1 << sl;
    const int j = t & (half - 1);
    const int pos = ((t >> sl) << (sl + 1)) + j;

    float ang = -PI2F * ((float)j * m_inv);
    float wi, wr;
    __sincosf(ang, &wi, &wr);

    float ur = re[pos],        ui = im[pos];
    float vr0 = re[pos + half], vi0 = im[pos + half];
    float vr = vr0 * wr - vi0 * wi;
    float vi = vr0 * wi + vi0 * wr;

    re[pos] = ur + vr;         im[pos] = ui + vi;
    re[pos + half] = ur - vr;  im[pos + half] = ui - vi;
}

// ---------------------------------------------------------------------------

extern "C" void kernel_launch(void* const* d_in, const int* in_sizes, int n_in,
                              void* d_out, int out_size, void* d_ws, size_t ws_size,
                              hipStream_t stream)
{
    const float* x = (const float*)d_in[0];
    const int N = in_sizes[0];
    int logN = 0;
    while ((1 << logN) < N) ++logN;

    float* outre = (float*)d_out;
    float* outim = outre + N;

    const bool ws_ok = ((logN & 1) == 0) &&
                       (ws_size >= (size_t)2 * (size_t)N * sizeof(float));

    if (ws_ok) {
        const int Nq = N >> 2;
        const int nb = (Nq + 255) / 256;
        float* wre = (float*)d_ws;
        float* wim = wre + N;

        // Pass 1: real input -> d_out
        hipLaunchKernelGGL(fft4_first, dim3(nb), dim3(256), 0, stream,
                           x, outre, outim, Nq, 1.0f / (float)N);

        // Passes 2..logN/2, ping-pong out <-> ws; odd pass count of the
        // remaining 12 alternations lands the final result in d_out.
        float* sre = outre; float* sim = outim;
        float* dre = wre;   float* dim_ = wim;
        const int npass = logN >> 1;  // 13
        for (int i = 2; i <= npass; ++i) {
            const int sl = 2 * (i - 1);
            const float n_inv = 1.0f / (float)(N >> sl);
            hipLaunchKernelGGL(fft4_pass, dim3(nb), dim3(256), 0, stream,
                               sre, sim, dre, dim_, Nq, sl, n_inv);
            float* t;
            t = sre; sre = dre; dre = t;
            t = sim; sim = dim_; dim_ = t;
        }
        // result now in d_out (sre == outre)
    } else {
        // In-place radix-2 fallback entirely within d_out.
        const int nbN = (N + 255) / 256;
        hipLaunchKernelGGL(bitrev_load, dim3(nbN), dim3(256), 0, stream,
                           x, outre, outim, N, logN);
        const int Nh = N >> 1;
        const int nbh = (Nh + 255) / 256;
        for (int s = 0; s < logN; ++s) {
            const float m_inv = 1.0f / (float)(2 << s);
            hipLaunchKernelGGL(r2_stage, dim3(nbh), dim3(256), 0, stream,
                               outre, outim, Nh, s, m_inv);
        }
    }
}

// Round 2
// 2371.276 us; speedup vs baseline: 1.0061x; 1.0061x over previous
//
#include <hip/hip_runtime.h>

#define PI2F 6.283185307179586476f

// ---------------------------------------------------------------------------
// Radix-4 Stockham autosort FFT (DIF), split re/im layout.
// Pass structure (OTFFT style): for current sub-length n, stride s (s*n/4 = N/4):
//   src indices: t, t+N/4, t+2N/4, t+3N/4      (t = q + s*p, perfectly coalesced)
//   dst indices: q + s*(4p + r), r = 0..3
//   y0 = (a+c)+(b+d)
//   y1 = ((a-c) - i(b-d)) * W_n^p
//   y2 = ((a+c)-(b+d))    * W_n^{2p}
//   y3 = ((a-c) + i(b-d)) * W_n^{3p}
// ---------------------------------------------------------------------------

// First pass: n = N, s = 1, real input (imag = 0), contiguous float4 stores.
__global__ __launch_bounds__(256) void fft4_first(const float* __restrict__ x,
                                                  float* __restrict__ yre,
                                                  float* __restrict__ yim,
                                                  int Nq, float n_inv)
{
    int p = blockIdx.x * 256 + threadIdx.x;
    if (p >= Nq) return;

    float a = x[p];
    float b = x[p + Nq];
    float c = x[p + 2 * Nq];
    float d = x[p + 3 * Nq];

    float apc = a + c, amc = a - c;
    float bpd = b + d, bmd = b - d;

    float ang = -PI2F * ((float)p * n_inv);
    float w1i, w1r;
    __sincosf(ang, &w1i, &w1r);
    float w2r = w1r * w1r - w1i * w1i, w2i = 2.f * w1r * w1i;
    float w3r = w2r * w1r - w2i * w1i, w3i = w2r * w1i + w2i * w1r;

    // y0 = (apc+bpd, 0)
    // y1 = (amc, -bmd) * w1
    // y2 = (apc-bpd, 0) * w2
    // y3 = (amc, +bmd) * w3
    float t2 = apc - bpd;
    float4 r4, i4;
    r4.x = apc + bpd;                 i4.x = 0.f;
    r4.y = amc * w1r + bmd * w1i;     i4.y = amc * w1i - bmd * w1r;
    r4.z = t2 * w2r;                  i4.z = t2 * w2i;
    r4.w = amc * w3r - bmd * w3i;     i4.w = amc * w3i + bmd * w3r;

    *(float4*)(yre + 4 * p) = r4;
    *(float4*)(yim + 4 * p) = i4;
}

// Generic radix-4 Stockham pass. sl = log2(s). n = N >> sl, n_inv = 1/n.
__global__ __launch_bounds__(256) void fft4_pass(const float* __restrict__ xre,
                                                 const float* __restrict__ xim,
                                                 float* __restrict__ yre,
                                                 float* __restrict__ yim,
                                                 int Nq, int sl, float n_inv)
{
    int t = blockIdx.x * 256 + threadIdx.x;
    if (t >= Nq) return;

    const int s = 1 << sl;
    const int q = t & (s - 1);
    const int p = t >> sl;

    float ar = xre[t],          ai = xim[t];
    float br = xre[t + Nq],     bi = xim[t + Nq];
    float cr = xre[t + 2 * Nq], ci = xim[t + 2 * Nq];
    float dr = xre[t + 3 * Nq], di = xim[t + 3 * Nq];

    float apcr = ar + cr, apci = ai + ci;
    float amcr = ar - cr, amci = ai - ci;
    float bpdr = br + dr, bpdi = bi + di;
    float bmdr = br - dr, bmdi = bi - di;

    float ang = -PI2F * ((float)p * n_inv);
    float w1i, w1r;
    __sincosf(ang, &w1i, &w1r);
    float w2r = w1r * w1r - w1i * w1i, w2i = 2.f * w1r * w1i;
    float w3r = w2r * w1r - w2i * w1i, w3i = w2r * w1i + w2i * w1r;

    const int dst = q + (p << (sl + 2));

    yre[dst] = apcr + bpdr;
    yim[dst] = apci + bpdi;

    // y1 = (amc - i*bmd) * w1 ; (amc - i*bmd) = (amcr + bmdi, amci - bmdr)
    float t1r = amcr + bmdi, t1i = amci - bmdr;
    yre[dst + s] = t1r * w1r - t1i * w1i;
    yim[dst + s] = t1r * w1i + t1i * w1r;

    float t2r = apcr - bpdr, t2i = apci - bpdi;
    yre[dst + 2 * s] = t2r * w2r - t2i * w2i;
    yim[dst + 2 * s] = t2r * w2i + t2i * w2r;

    // y3 = (amc + i*bmd) * w3 ; (amc + i*bmd) = (amcr - bmdi, amci + bmdr)
    float t3r = amcr - bmdi, t3i = amci + bmdr;
    yre[dst + 3 * s] = t3r * w3r - t3i * w3i;
    yim[dst + 3 * s] = t3r * w3i + t3i * w3r;
}

// ---------------------------------------------------------------------------
// Fallback (only if ws too small or log2(N) odd): in-place radix-2 DIT in
// d_out with bit-reversal gather. 26 stages. Slower but needs no workspace.
// ---------------------------------------------------------------------------
__global__ __launch_bounds__(256) void bitrev_load(const float* __restrict__ x,
                                                   float* __restrict__ re,
                                                   float* __restrict__ im,
                                                   int N, int logN)
{
    int i = blockIdx.x * 256 + threadIdx.x;
    if (i >= N) return;
    unsigned r = __brev((unsigned)i) >> (32 - logN);
    re[i] = x[r];
    im[i] = 0.f;
}

__global__ __launch_bounds__(256) void r2_stage(float* __restrict__ re,
                                                float* __restrict__ im,
                                                int Nh, int sl, float m_inv)
{
    int t = blockIdx.x * 256 + threadIdx.x;
    if (t >= Nh) return;
    const int half = 1 << sl;
    const int j = t & (half - 1);
    const int pos = ((t >> sl) << (sl + 1)) + j;

    float ang = -PI2F * ((float)j * m_inv);
    float wi, wr;
    __sincosf(ang, &wi, &wr);

    float ur = re[pos],        ui = im[pos];
    float vr0 = re[pos + half], vi0 = im[pos + half];
    float vr = vr0 * wr - vi0 * wi;
    float vi = vr0 * wi + vi0 * wr;

    re[pos] = ur + vr;         im[pos] = ui + vi;
    re[pos + half] = ur - vr;  im[pos + half] = ui - vi;
}

// ---------------------------------------------------------------------------

extern "C" void kernel_launch(void* const* d_in, const int* in_sizes, int n_in,
                              void* d_out, int out_size, void* d_ws, size_t ws_size,
                              hipStream_t stream)
{
    const float* x = (const float*)d_in[0];
    const int N = in_sizes[0];
    int logN = 0;
    while ((1 << logN) < N) ++logN;

    float* outre = (float*)d_out;
    float* outim = outre + N;

    const bool ws_ok = ((logN & 1) == 0) &&
                       (ws_size >= (size_t)2 * (size_t)N * sizeof(float));

    if (ws_ok) {
        const int Nq = N >> 2;
        const int nb = (Nq + 255) / 256;
        float* wre = (float*)d_ws;
        float* wim = wre + N;

        // Pass 1: real input -> d_out
        hipLaunchKernelGGL(fft4_first, dim3(nb), dim3(256), 0, stream,
                           x, outre, outim, Nq, 1.0f / (float)N);

        // Passes 2..logN/2, ping-pong out <-> ws; odd pass count of the
        // remaining 12 alternations lands the final result in d_out.
        float* sre = outre; float* sim = outim;
        float* dre = wre;   float* dim_ = wim;
        const int npass = logN >> 1;  // 13
        for (int i = 2; i <= npass; ++i) {
            const int sl = 2 * (i - 1);
            const float n_inv = 1.0f / (float)(N >> sl);
            hipLaunchKernelGGL(fft4_pass, dim3(nb), dim3(256), 0, stream,
                               sre, sim, dre, dim_, Nq, sl, n_inv);
            float* t;
            t = sre; sre = dre; dre = t;
            t = sim; sim = dim_; dim_ = t;
        }
        // result now in d_out (sre == outre)
    } else {
        // In-place radix-2 fallback entirely within d_out.
        const int nbN = (N + 255) / 256;
        hipLaunchKernelGGL(bitrev_load, dim3(nbN), dim3(256), 0, stream,
                           x, outre, outim, N, logN);
        const int Nh = N >> 1;
        const int nbh = (Nh + 255) / 256;
        for (int s = 0; s < logN; ++s) {
            const float m_inv = 1.0f / (float)(2 << s);
            hipLaunchKernelGGL(r2_stage, dim3(nbh), dim3(256), 0, stream,
                               outre, outim, Nh, s, m_inv);
        }
    }
}

// Round 3
// 2368.976 us; speedup vs baseline: 1.0070x; 1.0010x over previous
//
#include <hip/hip_runtime.h>

#define PI2F 6.283185307179586476f

// ---------------------------------------------------------------------------
// Radix-4 Stockham autosort FFT (DIF), split re/im layout.
// Pass structure (OTFFT style): for current sub-length n, stride s (s*n/4 = N/4):
//   src indices: t, t+N/4, t+2N/4, t+3N/4      (t = q + s*p, perfectly coalesced)
//   dst indices: q + s*(4p + r), r = 0..3
//   y0 = (a+c)+(b+d)
//   y1 = ((a-c) - i(b-d)) * W_n^p
//   y2 = ((a+c)-(b+d))    * W_n^{2p}
//   y3 = ((a-c) + i(b-d)) * W_n^{3p}
// ---------------------------------------------------------------------------

// First pass: n = N, s = 1, real input (imag = 0), contiguous float4 stores.
__global__ __launch_bounds__(256) void fft4_first(const float* __restrict__ x,
                                                  float* __restrict__ yre,
                                                  float* __restrict__ yim,
                                                  int Nq, float n_inv)
{
    int p = blockIdx.x * 256 + threadIdx.x;
    if (p >= Nq) return;

    float a = x[p];
    float b = x[p + Nq];
    float c = x[p + 2 * Nq];
    float d = x[p + 3 * Nq];

    float apc = a + c, amc = a - c;
    float bpd = b + d, bmd = b - d;

    float ang = -PI2F * ((float)p * n_inv);
    float w1i, w1r;
    __sincosf(ang, &w1i, &w1r);
    float w2r = w1r * w1r - w1i * w1i, w2i = 2.f * w1r * w1i;
    float w3r = w2r * w1r - w2i * w1i, w3i = w2r * w1i + w2i * w1r;

    // y0 = (apc+bpd, 0)
    // y1 = (amc, -bmd) * w1
    // y2 = (apc-bpd, 0) * w2
    // y3 = (amc, +bmd) * w3
    float t2 = apc - bpd;
    float4 r4, i4;
    r4.x = apc + bpd;                 i4.x = 0.f;
    r4.y = amc * w1r + bmd * w1i;     i4.y = amc * w1i - bmd * w1r;
    r4.z = t2 * w2r;                  i4.z = t2 * w2i;
    r4.w = amc * w3r - bmd * w3i;     i4.w = amc * w3i + bmd * w3r;

    *(float4*)(yre + 4 * p) = r4;
    *(float4*)(yim + 4 * p) = i4;
}

// Generic radix-4 Stockham pass. sl = log2(s). n = N >> sl, n_inv = 1/n.
__global__ __launch_bounds__(256) void fft4_pass(const float* __restrict__ xre,
                                                 const float* __restrict__ xim,
                                                 float* __restrict__ yre,
                                                 float* __restrict__ yim,
                                                 int Nq, int sl, float n_inv)
{
    int t = blockIdx.x * 256 + threadIdx.x;
    if (t >= Nq) return;

    const int s = 1 << sl;
    const int q = t & (s - 1);
    const int p = t >> sl;

    float ar = xre[t],          ai = xim[t];
    float br = xre[t + Nq],     bi = xim[t + Nq];
    float cr = xre[t + 2 * Nq], ci = xim[t + 2 * Nq];
    float dr = xre[t + 3 * Nq], di = xim[t + 3 * Nq];

    float apcr = ar + cr, apci = ai + ci;
    float amcr = ar - cr, amci = ai - ci;
    float bpdr = br + dr, bpdi = bi + di;
    float bmdr = br - dr, bmdi = bi - di;

    float ang = -PI2F * ((float)p * n_inv);
    float w1i, w1r;
    __sincosf(ang, &w1i, &w1r);
    float w2r = w1r * w1r - w1i * w1i, w2i = 2.f * w1r * w1i;
    float w3r = w2r * w1r - w2i * w1i, w3i = w2r * w1i + w2i * w1r;

    const int dst = q + (p << (sl + 2));

    yre[dst] = apcr + bpdr;
    yim[dst] = apci + bpdi;

    // y1 = (amc - i*bmd) * w1 ; (amc - i*bmd) = (amcr + bmdi, amci - bmdr)
    float t1r = amcr + bmdi, t1i = amci - bmdr;
    yre[dst + s] = t1r * w1r - t1i * w1i;
    yim[dst + s] = t1r * w1i + t1i * w1r;

    float t2r = apcr - bpdr, t2i = apci - bpdi;
    yre[dst + 2 * s] = t2r * w2r - t2i * w2i;
    yim[dst + 2 * s] = t2r * w2i + t2i * w2r;

    // y3 = (amc + i*bmd) * w3 ; (amc + i*bmd) = (amcr - bmdi, amci + bmdr)
    float t3r = amcr - bmdi, t3i = amci + bmdr;
    yre[dst + 3 * s] = t3r * w3r - t3i * w3i;
    yim[dst + 3 * s] = t3r * w3i + t3i * w3r;
}

// ---------------------------------------------------------------------------
// Fallback (only if ws too small or log2(N) odd): in-place radix-2 DIT in
// d_out with bit-reversal gather. 26 stages. Slower but needs no workspace.
// ---------------------------------------------------------------------------
__global__ __launch_bounds__(256) void bitrev_load(const float* __restrict__ x,
                                                   float* __restrict__ re,
                                                   float* __restrict__ im,
                                                   int N, int logN)
{
    int i = blockIdx.x * 256 + threadIdx.x;
    if (i >= N) return;
    unsigned r = __brev((unsigned)i) >> (32 - logN);
    re[i] = x[r];
    im[i] = 0.f;
}

__global__ __launch_bounds__(256) void r2_stage(float* __restrict__ re,
                                                float* __restrict__ im,
                                                int Nh, int sl, float m_inv)
{
    int t = blockIdx.x * 256 + threadIdx.x;
    if (t >= Nh) return;
    const int half = 1 << sl;
    const int j = t & (half - 1);
    const int pos = ((t >> sl) << (sl + 1)) + j;

    float ang = -PI2F * ((float)j * m_inv);
    float wi, wr;
    __sincosf(ang, &wi, &wr);

    float ur = re[pos],        ui = im[pos];
    float vr0 = re[pos + half], vi0 = im[pos + half];
    float vr = vr0 * wr - vi0 * wi;
    float vi = vr0 * wi + vi0 * wr;

    re[pos] = ur + vr;         im[pos] = ui + vi;
    re[pos + half] = ur - vr;  im[pos + half] = ui - vi;
}

// ---------------------------------------------------------------------------

extern "C" void kernel_launch(void* const* d_in, const int* in_sizes, int n_in,
                              void* d_out, int out_size, void* d_ws, size_t ws_size,
                              hipStream_t stream)
{
    const float* x = (const float*)d_in[0];
    const int N = in_sizes[0];
    int logN = 0;
    while ((1 << logN) < N) ++logN;

    float* outre = (float*)d_out;
    float* outim = outre + N;

    const bool ws_ok = ((logN & 1) == 0) &&
                       (ws_size >= (size_t)2 * (size_t)N * sizeof(float));

    if (ws_ok) {
        const int Nq = N >> 2;
        const int nb = (Nq + 255) / 256;
        float* wre = (float*)d_ws;
        float* wim = wre + N;

        // Pass 1: real input -> d_out
        hipLaunchKernelGGL(fft4_first, dim3(nb), dim3(256), 0, stream,
                           x, outre, outim, Nq, 1.0f / (float)N);

        // Passes 2..logN/2, ping-pong out <-> ws; odd pass count of the
        // remaining 12 alternations lands the final result in d_out.
        float* sre = outre; float* sim = outim;
        float* dre = wre;   float* dim_ = wim;
        const int npass = logN >> 1;  // 13
        for (int i = 2; i <= npass; ++i) {
            const int sl = 2 * (i - 1);
            const float n_inv = 1.0f / (float)(N >> sl);
            hipLaunchKernelGGL(fft4_pass, dim3(nb), dim3(256), 0, stream,
                               sre, sim, dre, dim_, Nq, sl, n_inv);
            float* t;
            t = sre; sre = dre; dre = t;
            t = sim; sim = dim_; dim_ = t;
        }
        // result now in d_out (sre == outre)
    } else {
        // In-place radix-2 fallback entirely within d_out.
        const int nbN = (N + 255) / 256;
        hipLaunchKernelGGL(bitrev_load, dim3(nbN), dim3(256), 0, stream,
                           x, outre, outim, N, logN);
        const int Nh = N >> 1;
        const int nbh = (Nh + 255) / 256;
        for (int s = 0; s < logN; ++s) {
            const float m_inv = 1.0f / (float)(2 << s);
            hipLaunchKernelGGL(r2_stage, dim3(nbh), dim3(256), 0, stream,
                               outre, outim, Nh, s, m_inv);
        }
    }
}

// Round 4
// 1159.624 us; speedup vs baseline: 2.0573x; 2.0429x over previous
//
#include <hip/hip_runtime.h>

#define PI2F 6.283185307179586476f

// ---------------------------------------------------------------------------
// Pass 1: radix-4 Stockham, n = N, s = 1, real input (imag = 0).
// Contiguous float4 stores. (Verified in the 13-pass version.)
// ---------------------------------------------------------------------------
__global__ __launch_bounds__(256) void fft4_first(const float* __restrict__ x,
                                                  float* __restrict__ yre,
                                                  float* __restrict__ yim,
                                                  int Nq, float n_inv)
{
    int p = blockIdx.x * 256 + threadIdx.x;
    if (p >= Nq) return;

    float a = x[p];
    float b = x[p + Nq];
    float c = x[p + 2 * Nq];
    float d = x[p + 3 * Nq];

    float apc = a + c, amc = a - c;
    float bpd = b + d, bmd = b - d;

    float ang = -PI2F * ((float)p * n_inv);
    float w1i, w1r;
    __sincosf(ang, &w1i, &w1r);
    float w2r = w1r * w1r - w1i * w1i, w2i = 2.f * w1r * w1i;
    float w3r = w2r * w1r - w2i * w1i, w3i = w2r * w1i + w2i * w1r;

    float t2 = apc - bpd;
    float4 r4, i4;
    r4.x = apc + bpd;                 i4.x = 0.f;
    r4.y = amc * w1r + bmd * w1i;     i4.y = amc * w1i - bmd * w1r;
    r4.z = t2 * w2r;                  i4.z = t2 * w2i;
    r4.w = amc * w3r - bmd * w3i;     i4.w = amc * w3i + bmd * w3r;

    *(float4*)(yre + 4 * p) = r4;
    *(float4*)(yim + 4 * p) = i4;
}

// ---------------------------------------------------------------------------
// 16-point DFT, natural order in/out, fully unrolled (two radix-4 layers).
// X[r] = sum_j a[j] W_16^{jr}.  Layer1: radix-4 over jh (j = jl + 4*jh),
// result B[jl][rl] stored at pos jl + 4*rl; twiddle W_16^{jl*rl};
// Layer2: radix-4 over jl, output X[rl + 4*rh].
// ---------------------------------------------------------------------------
__device__ __forceinline__ void dft16(float* xr, float* xi)
{
    // twiddle table W_16^{e(pos)}, e = (pos&3)*(pos>>2)
    const float W16R[16] = {1.f, 1.f, 1.f, 1.f,
                            1.f, 0.92387953251f, 0.70710678119f, 0.38268343236f,
                            1.f, 0.70710678119f, 0.f, -0.70710678119f,
                            1.f, 0.38268343236f, -0.70710678119f, -0.92387953251f};
    const float W16I[16] = {0.f, 0.f, 0.f, 0.f,
                            0.f, -0.38268343236f, -0.70710678119f, -0.92387953251f,
                            0.f, -0.70710678119f, -1.f, -0.70710678119f,
                            0.f, -0.92387953251f, -0.70710678119f, 0.38268343236f};

    float br[16], bi[16];
#pragma unroll
    for (int jl = 0; jl < 4; ++jl) {
        float a0r = xr[jl],      a0i = xi[jl];
        float a1r = xr[jl + 4],  a1i = xi[jl + 4];
        float a2r = xr[jl + 8],  a2i = xi[jl + 8];
        float a3r = xr[jl + 12], a3i = xi[jl + 12];
        float s02r = a0r + a2r, s02i = a0i + a2i;
        float d02r = a0r - a2r, d02i = a0i - a2i;
        float s13r = a1r + a3r, s13i = a1i + a3i;
        float d13r = a1r - a3r, d13i = a1i - a3i;
        br[jl + 0]  = s02r + s13r;  bi[jl + 0]  = s02i + s13i;  // rl=0
        br[jl + 4]  = d02r + d13i;  bi[jl + 4]  = d02i - d13r;  // rl=1: d02 - i*d13
        br[jl + 8]  = s02r - s13r;  bi[jl + 8]  = s02i - s13i;  // rl=2
        br[jl + 12] = d02r - d13i;  bi[jl + 12] = d02i + d13r;  // rl=3: d02 + i*d13
    }
#pragma unroll
    for (int pos = 0; pos < 16; ++pos) {
        float wr = W16R[pos], wi = W16I[pos];
        float tr = br[pos] * wr - bi[pos] * wi;
        bi[pos]  = br[pos] * wi + bi[pos] * wr;
        br[pos]  = tr;
    }
#pragma unroll
    for (int rl = 0; rl < 4; ++rl) {
        float a0r = br[4 * rl + 0], a0i = bi[4 * rl + 0];
        float a1r = br[4 * rl + 1], a1i = bi[4 * rl + 1];
        float a2r = br[4 * rl + 2], a2i = bi[4 * rl + 2];
        float a3r = br[4 * rl + 3], a3i = bi[4 * rl + 3];
        float s02r = a0r + a2r, s02i = a0i + a2i;
        float d02r = a0r - a2r, d02i = a0i - a2i;
        float s13r = a1r + a3r, s13i = a1i + a3i;
        float d13r = a1r - a3r, d13i = a1i - a3i;
        xr[rl + 0]  = s02r + s13r;  xi[rl + 0]  = s02i + s13i;
        xr[rl + 4]  = d02r + d13i;  xi[rl + 4]  = d02i - d13r;
        xr[rl + 8]  = s02r - s13r;  xi[rl + 8]  = s02i - s13i;
        xr[rl + 12] = d02r - d13i;  xi[rl + 12] = d02i + d13r;
    }
}

// ---------------------------------------------------------------------------
// Workgroup-cooperative radix-256 Stockham pass.
// Sub-FFT for t = q + s*p:  a_j = x[t + j*(N/256)],
//   y_r = W_n^{p*r} * sum_j a_j W_256^{jr},  dst = q + s*(256p + r),  n = N/s.
// 256-pt DFT via 16x16 Cooley-Tukey: thread (f, j1) does the inner DFT over
// j2, applies combined twiddle W_n^{r1*(j1*(n/256)+p)}, LDS-transposes to
// thread (f, r1) which does the outer DFT over j1 and the W_{n/16}^{p*r2}
// twiddle. 16 sub-FFTs per 256-thread block; LDS 2*16.5KB, pad 257 to break
// bank conflicts (writes 2-way free, reads <=4-way).
// ---------------------------------------------------------------------------
__global__ __launch_bounds__(256) void fft256_pass(const float* __restrict__ xre,
                                                   const float* __restrict__ xim,
                                                   float* __restrict__ yre,
                                                   float* __restrict__ yim,
                                                   int Nq,        // N/256
                                                   int sl,        // log2(s)
                                                   float n_inv,   // 1/n
                                                   float n16_inv) // 16/n
{
    __shared__ float lre[16 * 257 + 16];
    __shared__ float lim[16 * 257 + 16];

    const int tid = threadIdx.x;
    const int f   = tid & 15;
    const int k   = tid >> 4;          // = j1 in phase A, = r1 in phase B
    const int t   = blockIdx.x * 16 + f;
    const int s   = 1 << sl;
    const int q   = t & (s - 1);
    const int p   = t >> sl;

    // ---- phase A: load + inner DFT over j2 + combined r1-twiddle ----
    float ar[16], ai[16];
    const int j1 = k;
#pragma unroll
    for (int j2 = 0; j2 < 16; ++j2) {
        int idx = t + (j1 + 16 * j2) * Nq;
        ar[j2] = xre[idx];
        ai[j2] = xim[idx];
    }

    dft16(ar, ai);   // ar[r1] = B[j1][r1]

    // W_256^{j1*r1} * W_n^{p*r1} = W_n^{r1*m}, m = j1*(n/256) + p  (exact < 2^24)
    const int   m  = j1 * (Nq >> sl) + p;
    const float mf = (float)m;
#pragma unroll
    for (int r1 = 1; r1 < 16; ++r1) {
        float ang = -PI2F * ((float)r1 * mf * n_inv);
        float sw, cw;
        __sincosf(ang, &sw, &cw);
        float tr = ar[r1] * cw - ai[r1] * sw;
        ai[r1]   = ar[r1] * sw + ai[r1] * cw;
        ar[r1]   = tr;
    }

    // ---- LDS transpose: (f, j1, r1) -> (f, r1, j1) ----
    const int wbase = f * 257 + j1 * 16;
#pragma unroll
    for (int r1 = 0; r1 < 16; ++r1) {
        lre[wbase + r1] = ar[r1];
        lim[wbase + r1] = ai[r1];
    }
    __syncthreads();

    // ---- phase B: outer DFT over j1 + second twiddle + store ----
    const int r1 = k;
    float er[16], ei[16];
#pragma unroll
    for (int jj = 0; jj < 16; ++jj) {
        er[jj] = lre[f * 257 + jj * 16 + r1];
        ei[jj] = lim[f * 257 + jj * 16 + r1];
    }

    dft16(er, ei);   // er[r2] = A[r1 + 16*r2] (before W_{n/16}^{p*r2})

    const int   dstbase = q + ((256 * p + r1) << sl);
    const float pf      = (float)p;
#pragma unroll
    for (int r2 = 0; r2 < 16; ++r2) {
        float ang = -PI2F * ((float)r2 * pf * n16_inv);
        float sw, cw;
        __sincosf(ang, &sw, &cw);
        float tr = er[r2] * cw - ei[r2] * sw;
        float ti = er[r2] * sw + ei[r2] * cw;
        int dst = dstbase + ((16 * r2) << sl);
        yre[dst] = tr;
        yim[dst] = ti;
    }
}

// ---------------------------------------------------------------------------
// Generic radix-4 Stockham pass (fallback path for non-2^26 sizes).
// ---------------------------------------------------------------------------
__global__ __launch_bounds__(256) void fft4_pass(const float* __restrict__ xre,
                                                 const float* __restrict__ xim,
                                                 float* __restrict__ yre,
                                                 float* __restrict__ yim,
                                                 int Nq, int sl, float n_inv)
{
    int t = blockIdx.x * 256 + threadIdx.x;
    if (t >= Nq) return;

    const int s = 1 << sl;
    const int q = t & (s - 1);
    const int p = t >> sl;

    float ar = xre[t],          ai = xim[t];
    float br = xre[t + Nq],     bi = xim[t + Nq];
    float cr = xre[t + 2 * Nq], ci = xim[t + 2 * Nq];
    float dr = xre[t + 3 * Nq], di = xim[t + 3 * Nq];

    float apcr = ar + cr, apci = ai + ci;
    float amcr = ar - cr, amci = ai - ci;
    float bpdr = br + dr, bpdi = bi + di;
    float bmdr = br - dr, bmdi = bi - di;

    float ang = -PI2F * ((float)p * n_inv);
    float w1i, w1r;
    __sincosf(ang, &w1i, &w1r);
    float w2r = w1r * w1r - w1i * w1i, w2i = 2.f * w1r * w1i;
    float w3r = w2r * w1r - w2i * w1i, w3i = w2r * w1i + w2i * w1r;

    const int dst = q + (p << (sl + 2));

    yre[dst] = apcr + bpdr;
    yim[dst] = apci + bpdi;

    float t1r = amcr + bmdi, t1i = amci - bmdr;
    yre[dst + s] = t1r * w1r - t1i * w1i;
    yim[dst + s] = t1r * w1i + t1i * w1r;

    float t2r = apcr - bpdr, t2i = apci - bpdi;
    yre[dst + 2 * s] = t2r * w2r - t2i * w2i;
    yim[dst + 2 * s] = t2r * w2i + t2i * w2r;

    float t3r = amcr - bmdi, t3i = amci + bmdr;
    yre[dst + 3 * s] = t3r * w3r - t3i * w3i;
    yim[dst + 3 * s] = t3r * w3i + t3i * w3r;
}

// ---------------------------------------------------------------------------
// Last-resort fallback: in-place radix-2 DIT in d_out (no workspace).
// ---------------------------------------------------------------------------
__global__ __launch_bounds__(256) void bitrev_load(const float* __restrict__ x,
                                                   float* __restrict__ re,
                                                   float* __restrict__ im,
                                                   int N, int logN)
{
    int i = blockIdx.x * 256 + threadIdx.x;
    if (i >= N) return;
    unsigned r = __brev((unsigned)i) >> (32 - logN);
    re[i] = x[r];
    im[i] = 0.f;
}

__global__ __launch_bounds__(256) void r2_stage(float* __restrict__ re,
                                                float* __restrict__ im,
                                                int Nh, int sl, float m_inv)
{
    int t = blockIdx.x * 256 + threadIdx.x;
    if (t >= Nh) return;
    const int half = 1 << sl;
    const int j = t & (half - 1);
    const int pos = ((t >> sl) << (sl + 1)) + j;

    float ang = -PI2F * ((float)j * m_inv);
    float wi, wr;
    __sincosf(ang, &wi, &wr);

    float ur = re[pos],         ui = im[pos];
    float vr0 = re[pos + half], vi0 = im[pos + half];
    float vr = vr0 * wr - vi0 * wi;
    float vi = vr0 * wi + vi0 * wr;

    re[pos] = ur + vr;         im[pos] = ui + vi;
    re[pos + half] = ur - vr;  im[pos + half] = ui - vi;
}

// ---------------------------------------------------------------------------

extern "C" void kernel_launch(void* const* d_in, const int* in_sizes, int n_in,
                              void* d_out, int out_size, void* d_ws, size_t ws_size,
                              hipStream_t stream)
{
    const float* x = (const float*)d_in[0];
    const int N = in_sizes[0];
    int logN = 0;
    while ((1 << logN) < N) ++logN;

    float* outre = (float*)d_out;
    float* outim = outre + N;

    const bool ws_ok = (ws_size >= (size_t)2 * (size_t)N * sizeof(float));
    float* wre = (float*)d_ws;
    float* wim = wre + N;

    if (logN == 26 && ws_ok) {
        // 26 = 2 + 8 + 8 + 8: radix-4 (real input) then 3x radix-256.
        const int Nq4 = N >> 2;
        hipLaunchKernelGGL(fft4_first, dim3(Nq4 / 256), dim3(256), 0, stream,
                           x, wre, wim, Nq4, 1.0f / (float)N);
        const int Nq = N >> 8;
        const int blocks = N >> 12;      // (N/256)/16 sub-FFT groups
        const float fN = (float)N;
        // pass 2: s = 4,      n = N/4    = 2^24
        hipLaunchKernelGGL(fft256_pass, dim3(blocks), dim3(256), 0, stream,
                           wre, wim, outre, outim, Nq, 2, 4.0f / fN, 64.0f / fN);
        // pass 3: s = 1024,   n = N/1024 = 2^16
        hipLaunchKernelGGL(fft256_pass, dim3(blocks), dim3(256), 0, stream,
                           outre, outim, wre, wim, Nq, 10, 1024.0f / fN, 16384.0f / fN);
        // pass 4: s = 2^18,   n = 256
        hipLaunchKernelGGL(fft256_pass, dim3(blocks), dim3(256), 0, stream,
                           wre, wim, outre, outim, Nq, 18, 1.0f / 256.0f, 1.0f / 16.0f);
        // result in d_out
    } else if (((logN & 1) == 0) && ws_ok) {
        // Generic radix-4 Stockham (13 passes at 2^26), verified path.
        const int Nq = N >> 2;
        const int nb = (Nq + 255) / 256;
        hipLaunchKernelGGL(fft4_first, dim3(nb), dim3(256), 0, stream,
                           x, outre, outim, Nq, 1.0f / (float)N);
        float* sre = outre; float* sim = outim;
        float* dre = wre;   float* dim_ = wim;
        const int npass = logN >> 1;
        for (int i = 2; i <= npass; ++i) {
            const int sl = 2 * (i - 1);
            const float n_inv = 1.0f / (float)(N >> sl);
            hipLaunchKernelGGL(fft4_pass, dim3(nb), dim3(256), 0, stream,
                               sre, sim, dre, dim_, Nq, sl, n_inv);
            float* tt;
            tt = sre; sre = dre; dre = tt;
            tt = sim; sim = dim_; dim_ = tt;
        }
    } else {
        const int nbN = (N + 255) / 256;
        hipLaunchKernelGGL(bitrev_load, dim3(nbN), dim3(256), 0, stream,
                           x, outre, outim, N, logN);
        const int Nh = N >> 1;
        const int nbh = (Nh + 255) / 256;
        for (int s = 0; s < logN; ++s) {
            const float m_inv = 1.0f / (float)(2 << s);
            hipLaunchKernelGGL(r2_stage, dim3(nbh), dim3(256), 0, stream,
                               outre, outim, Nh, s, m_inv);
        }
    }
}